// Round 7
// baseline (175.520 us; speedup 1.0000x reference)
//
#include <hip/hip_runtime.h>
#include <cstdint>

using u16 = unsigned short;
typedef __bf16 bf16x8 __attribute__((ext_vector_type(8)));
typedef __bf16 bf16x4 __attribute__((ext_vector_type(4)));
typedef __bf16 bf16x2 __attribute__((ext_vector_type(2)));
typedef float f32x4 __attribute__((ext_vector_type(4)));

#define MFMA16(a, b, c) __builtin_amdgcn_mfma_f32_16x16x32_bf16((a), (b), (c), 0, 0, 0)

__device__ __forceinline__ u16 f2bf(float f) {
  union { float f; uint32_t u; } c; c.f = f;
  uint32_t u = c.u;
  u += 0x7fffu + ((u >> 16) & 1u);   // RNE
  return (u16)(u >> 16);
}

#if __has_builtin(__builtin_amdgcn_global_load_lds)
#define GLOAD_LDS16(g, l)                                                      \
  __builtin_amdgcn_global_load_lds(                                            \
      (__attribute__((address_space(1))) void*)(g),                            \
      (__attribute__((address_space(3))) void*)(l), 16, 0, 0)
#else
#define GLOAD_LDS16(g, l) do { *(uint4*)(l) = *(const uint4*)(g); } while (0)
#endif

// In-register P^T fragment build.
// lo covers k_local 0..15, hi k_local 16..31 (C-layout quad*4+r rows);
// output B-fragment: lane(quad,l16) holds P[k_local = quad*8 + j][q=l16].
__device__ __forceinline__ bf16x8 ptrans(const f32x4 lo, const f32x4 hi) {
  union W { bf16x2 h; uint32_t u; } wl0, wl1, wh0, wh1;
  wl0.h[0] = (__bf16)lo[0]; wl0.h[1] = (__bf16)lo[1];
  wl1.h[0] = (__bf16)lo[2]; wl1.h[1] = (__bf16)lo[3];
  wh0.h[0] = (__bf16)hi[0]; wh0.h[1] = (__bf16)hi[1];
  wh1.h[0] = (__bf16)hi[2]; wh1.h[1] = (__bf16)hi[3];
  uint32_t a0 = wl0.u, b0 = wh0.u, a1 = wl1.u, b1 = wh1.u;
  asm("v_permlane32_swap_b32 %0, %1" : "+v"(a0), "+v"(b0));
  asm("v_permlane16_swap_b32 %0, %1" : "+v"(a0), "+v"(b0));
  asm("v_permlane32_swap_b32 %0, %1" : "+v"(a1), "+v"(b1));
  asm("v_permlane16_swap_b32 %0, %1" : "+v"(a1), "+v"(b1));
  union R { uint32_t u[4]; bf16x8 v; } r;
  r.u[0] = a0; r.u[1] = a1; r.u[2] = b0; r.u[3] = b1;
  return r.v;
}

// ---------------- fused prep: x->bf16, w_qkv^T->bf16, w_out^T->bf16 --------
__global__ __launch_bounds__(256) void prep(
    const float* __restrict__ x, const float* __restrict__ w_qkv,
    const float* __restrict__ w_out, u16* __restrict__ xb,
    u16* __restrict__ wqT, u16* __restrict__ woT) {
  const int bid = blockIdx.x, tid = threadIdx.x;
  if (bid < 4096) {
    int i = (bid * 256 + tid) * 4;
    float4 v = *(const float4*)&x[i];
    ushort4 p;
    p.x = f2bf(v.x); p.y = f2bf(v.y); p.z = f2bf(v.z); p.w = f2bf(v.w);
    *(ushort4*)&xb[i] = p;
    return;
  }
  __shared__ float tile[32][33];
  int t = bid - 4096;
  const float* in;
  u16* outp;
  int C, bx, by;
  if (t < 3072) { in = w_qkv; outp = wqT; C = 3072; bx = (t % 96) * 32; by = (t / 96) * 32; }
  else { t -= 3072; in = w_out; outp = woT; C = 1024; bx = (t % 32) * 32; by = (t / 32) * 32; }
  const int tx = tid & 31, ty = tid >> 5;
#pragma unroll
  for (int r2 = 0; r2 < 4; ++r2)
    tile[ty + r2 * 8][tx] = in[(size_t)(by + ty + r2 * 8) * C + bx + tx];
  __syncthreads();
#pragma unroll
  for (int r2 = 0; r2 < 4; ++r2)
    outp[(size_t)(bx + ty + r2 * 8) * 1024 + by + tx] = f2bf(tile[tx][ty + r2 * 8]);
}

// ---------------- GEMM 128x128 (R10, best measured): QKV scatter -----------
__global__ __launch_bounds__(256, 3) void gemm_qkv(
    const u16* __restrict__ A, const u16* __restrict__ Bt,
    const float* __restrict__ bias,
    u16* __restrict__ qb, u16* __restrict__ kb, u16* __restrict__ vb,
    int M, int N, int K) {
  __shared__ u16 As[128 * 32];
  __shared__ u16 Bs[128 * 32];
  const int tid = threadIdx.x;
  const int m0 = blockIdx.x * 128;
  const int n0 = blockIdx.y * 128;
  const int lane = tid & 63, w = tid >> 6;
  const int quad = lane >> 4, l16 = lane & 15;
  const int wr = w >> 1, wc = w & 1;

  f32x4 acc[4][4] = {};

  const int r0 = tid >> 2, p0 = tid & 3;
  const int r1 = r0 + 64;
  const int c8 = p0 ^ ((r0 >> 1) & 3);
  const u16* ga0 = A + (size_t)(m0 + r0) * K + c8 * 8;
  const u16* ga1 = A + (size_t)(m0 + r1) * K + c8 * 8;
  const u16* gb0 = Bt + (size_t)(n0 + r0) * K + c8 * 8;
  const u16* gb1 = Bt + (size_t)(n0 + r1) * K + c8 * 8;
  u16* la0 = &As[tid * 8];
  u16* la1 = &As[(tid + 256) * 8];
  u16* lb0 = &Bs[tid * 8];
  u16* lb1 = &Bs[(tid + 256) * 8];

  int aoff[4], boff[4];
#pragma unroll
  for (int i = 0; i < 4; ++i) {
    int ra = wr * 64 + i * 16 + l16;
    aoff[i] = (ra * 4 + (quad ^ ((ra >> 1) & 3))) * 8;
    int rb = wc * 64 + i * 16 + l16;
    boff[i] = (rb * 4 + (quad ^ ((rb >> 1) & 3))) * 8;
  }

  const int nIter = K >> 5;
  for (int kt = 0; kt < nIter; ++kt) {
    __syncthreads();
    const int kk = kt << 5;
    GLOAD_LDS16(ga0 + kk, la0);
    GLOAD_LDS16(ga1 + kk, la1);
    GLOAD_LDS16(gb0 + kk, lb0);
    GLOAD_LDS16(gb1 + kk, lb1);
    __syncthreads();
    bf16x8 af[4], bfr[4];
#pragma unroll
    for (int i = 0; i < 4; ++i) af[i] = *(const bf16x8*)&As[aoff[i]];
#pragma unroll
    for (int j = 0; j < 4; ++j) bfr[j] = *(const bf16x8*)&Bs[boff[j]];
#pragma unroll
    for (int i = 0; i < 4; ++i)
#pragma unroll
      for (int j = 0; j < 4; ++j)
        acc[i][j] = MFMA16(af[i], bfr[j], acc[i][j]);
  }

  const int S = 2048, NH = 16;
#pragma unroll
  for (int i = 0; i < 4; ++i) {
    const int mb = m0 + wr * 64 + i * 16 + quad * 4;
#pragma unroll
    for (int j = 0; j < 4; ++j) {
      const int n = n0 + wc * 64 + j * 16 + l16;
      const float bv = bias[n];
      const int which = n >> 10;      // 0:Q 1:K 2:V (uniform per block)
      const int hn = n & 1023;
      const int h = hn >> 6, d = hn & 63;
      const int b = mb >> 11, s = mb & 2047;
      const int bh = b * NH + h;
      if (which == 2) {
        ushort4 pk;
        pk.x = f2bf(acc[i][j][0] + bv);
        pk.y = f2bf(acc[i][j][1] + bv);
        pk.z = f2bf(acc[i][j][2] + bv);
        pk.w = f2bf(acc[i][j][3] + bv);
        *(ushort4*)&vb[((size_t)bh * 64 + d) * S + s] = pk;  // V transposed
      } else {
        // Q pre-scaled by HD^-0.5 * log2(e): scores land in exp2 domain
        const float sc = (which == 0) ? 0.18033688f : 1.0f;
        u16* dst = (which == 0) ? qb : kb;
#pragma unroll
        for (int r = 0; r < 4; ++r)
          dst[((size_t)bh * S + s + r) * 64 + d] = f2bf((acc[i][j][r] + bv) * sc);
      }
    }
  }
}

// ---------------- GEMM 64x128: out = A @ Bt^T + bias (fp32 out) ----------
__global__ __launch_bounds__(256, 2) void gemm_out(
    const u16* __restrict__ A, const u16* __restrict__ Bt,
    const float* __restrict__ bias, float* __restrict__ outf,
    int M, int N, int K) {
  __shared__ u16 As[64 * 32];
  __shared__ u16 Bs[128 * 32];
  const int tid = threadIdx.x;
  const int m0 = blockIdx.x * 64;
  const int n0 = blockIdx.y * 128;
  const int lane = tid & 63, w = tid >> 6;
  const int quad = lane >> 4, l16 = lane & 15;
  const int wr = w >> 1, wc = w & 1;

  f32x4 acc[2][4] = {};

  const int r0 = tid >> 2, p0 = tid & 3;
  const int c8 = p0 ^ ((r0 >> 1) & 3);
  const u16* ga0 = A + (size_t)(m0 + r0) * K + c8 * 8;
  const u16* gb0 = Bt + (size_t)(n0 + r0) * K + c8 * 8;
  const u16* gb1 = Bt + (size_t)(n0 + r0 + 64) * K + c8 * 8;
  u16* la0 = &As[tid * 8];
  u16* lb0 = &Bs[tid * 8];
  u16* lb1 = &Bs[(tid + 256) * 8];

  int aoff[2], boff[4];
#pragma unroll
  for (int i = 0; i < 2; ++i) {
    int ra = wr * 32 + i * 16 + l16;
    aoff[i] = (ra * 4 + (quad ^ ((ra >> 1) & 3))) * 8;
  }
#pragma unroll
  for (int j = 0; j < 4; ++j) {
    int rb = wc * 64 + j * 16 + l16;
    boff[j] = (rb * 4 + (quad ^ ((rb >> 1) & 3))) * 8;
  }

  const int nIter = K >> 5;
  for (int kt = 0; kt < nIter; ++kt) {
    __syncthreads();
    const int kk = kt << 5;
    GLOAD_LDS16(ga0 + kk, la0);
    GLOAD_LDS16(gb0 + kk, lb0);
    GLOAD_LDS16(gb1 + kk, lb1);
    __syncthreads();
    bf16x8 af[2], bfr[4];
#pragma unroll
    for (int i = 0; i < 2; ++i) af[i] = *(const bf16x8*)&As[aoff[i]];
#pragma unroll
    for (int j = 0; j < 4; ++j) bfr[j] = *(const bf16x8*)&Bs[boff[j]];
#pragma unroll
    for (int i = 0; i < 2; ++i)
#pragma unroll
      for (int j = 0; j < 4; ++j)
        acc[i][j] = MFMA16(af[i], bfr[j], acc[i][j]);
  }

#pragma unroll
  for (int i = 0; i < 2; ++i) {
    const int mb = m0 + wr * 32 + i * 16 + quad * 4;
#pragma unroll
    for (int j = 0; j < 4; ++j) {
      const int n = n0 + wc * 64 + j * 16 + l16;
      const float bv = bias[n];
#pragma unroll
      for (int r = 0; r < 4; ++r)
        outf[(size_t)(mb + r) * N + n] = acc[i][j][r] + bv;
    }
  }
}

// ---------------- flash attention v15: 2x2 (q-half, key-half) wave split ---
// v14 post-mortem: pipelining did NOT raise MfmaUtil -> revert to v13 tile
// structure. Pipe accounting: per CU per tile, 8 waves x 32 ds_read_b128 =
// 3072 cyc on the LDS port vs 2794 cyc MFMA demand -> LDS reads (each wave
// redundantly reading the FULL K+V tile) are the widest pipe. v15: waves
// split 2x2 over (wq = q-half, wk = key-half). Each wave computes
// S^T[64k x 64q] for its key-half: 8 K-reads + 8 V-reads (V's hh index ==
// wk, no relayout needed) = 16 reads/wave/tile (half). Same per-wave MFMA/
// exp2/ptrans counts. One-time cross-wk reduce of accO/accL through LDS
// (conflict-free f32x4 layout, reuses Ks/Vs, 2 barriers) at the end.
__global__ __launch_bounds__(256, 2) void attn_fa(
    const u16* __restrict__ qg, const u16* __restrict__ kg,
    const u16* __restrict__ vg, u16* __restrict__ o) {
  const int S = 2048;
  const int lin = blockIdx.x;
  const int xcd = lin & 7, chunk = lin >> 3;
  const int bh = xcd * 4 + (chunk & 3);
  const int qblk = chunk >> 2;
  const int b = bh >> 4, h = bh & 15;
  const int tid = threadIdx.x, w = tid >> 6, lane = tid & 63;
  const int quad = lane >> 4, l16 = lane & 15;
  const int wq = w >> 1, wk = w & 1;

  __shared__ u16 Ks[2][8192];   // [128 key-rows][8 granules], ^(row&7) swizzle
  __shared__ u16 Vs[2][8192];   // [2 hh][64 d-rows][8 granules], ^(row&7)

  const int q0w = qblk * 128 + wq * 64;
  // Q B-frags qf[qt][dh]: lane holds Q[q = q0w+qt*16+l16][d = dh*32+quad*8+j]
  bf16x8 qf[4][2];
#pragma unroll
  for (int qt = 0; qt < 4; ++qt)
#pragma unroll
    for (int dh = 0; dh < 2; ++dh)
      qf[qt][dh] = *(const bf16x8*)(qg + ((size_t)bh * S + q0w + qt * 16 + l16) * 64 +
                                    dh * 32 + quad * 8);

  f32x4 accO[4][4] = {};   // [dt][qt]
  f32x4 accL[4] = {};      // [qt] rowsums (ones-MFMA)

  bf16x8 ones;
#pragma unroll
  for (int i = 0; i < 8; ++i) ones[i] = (__bf16)1.0f;

  const u16* kbase = kg + (size_t)bh * S * 64;
  const u16* vbase = vg + (size_t)bh * 64 * S;

  // staging roles (tid-based, wave-independent) -- unchanged from v13
  const int sr0 = tid >> 3, sp0 = tid & 7;
  const int c8s = sp0 ^ (sr0 & 7);
  const u16* kSrc = kbase + (size_t)sr0 * 64 + c8s * 8;
  const u16* vSrc = vbase + (size_t)sr0 * S + c8s * 8;

  const int kgA = (quad ^ (l16 & 7)) * 8;
  const int kgB = ((quad + 4) ^ (l16 & 7)) * 8;

#define STAGE_KV(KT, NB)                                                      \
  {                                                                           \
    _Pragma("unroll")                                                         \
    for (int seg = 0; seg < 4; ++seg) {                                       \
      GLOAD_LDS16(kSrc + (size_t)((KT) * 128 + seg * 32) * 64,                \
                  &Ks[NB][(seg * 256 + tid) * 8]);                            \
      GLOAD_LDS16(vSrc + (size_t)(seg & 1) * 32 * S + (KT) * 128 +            \
                      (seg >> 1) * 64,                                        \
                  &Vs[NB][(seg * 256 + tid) * 8]);                            \
    }                                                                         \
  }

  // preload tile 0 into buffer 0
  STAGE_KV(0, 0);

  for (int kt = 0; kt < 16; ++kt) {
    const int cur = kt & 1;
    __syncthreads();  // glds(kt) landed; all buf[cur^1] reads complete
    const u16* Kc = Ks[cur];
    const u16* Vc = Vs[cur];

    // ---- K frags for this wave's key-half (8 ds_read_b128) ----
    bf16x8 kf[4][2];
#pragma unroll
    for (int ct = 0; ct < 4; ++ct) {
      const int rb = (wk * 64 + ct * 16 + l16) * 64;
      kf[ct][0] = *(const bf16x8*)&Kc[rb + kgA];
      kf[ct][1] = *(const bf16x8*)&Kc[rb + kgB];
    }

    // ---- prefetch next tile (glds overlap QK/exp2) ----
    if (kt + 1 < 16) STAGE_KV(kt + 1, cur ^ 1);

    // ---- S^T = K Q^T: s[ct][qt], 32 MFMA ----
    f32x4 s[4][4] = {};
    __builtin_amdgcn_s_setprio(1);
#pragma unroll
    for (int ct = 0; ct < 4; ++ct)
#pragma unroll
      for (int qt = 0; qt < 4; ++qt) {
        s[ct][qt] = MFMA16(kf[ct][0], qf[qt][0], s[ct][qt]);
        s[ct][qt] = MFMA16(kf[ct][1], qf[qt][1], s[ct][qt]);
      }
    __builtin_amdgcn_s_setprio(0);

    // ---- P = exp2(s) ----
#pragma unroll
    for (int ct = 0; ct < 4; ++ct)
#pragma unroll
      for (int qt = 0; qt < 4; ++qt)
#pragma unroll
        for (int r = 0; r < 4; ++r)
          s[ct][qt][r] = __builtin_amdgcn_exp2f(s[ct][qt][r]);

    // ---- P^T fragments: pf[kt32][qt] ----
    bf16x8 pf[2][4];
#pragma unroll
    for (int qt = 0; qt < 4; ++qt) {
      pf[0][qt] = ptrans(s[0][qt], s[1][qt]);
      pf[1][qt] = ptrans(s[2][qt], s[3][qt]);
    }

    // ---- V frags for this wave's key-half (8 ds_read_b128, hh = wk) ----
    bf16x8 vf[4][2];
#pragma unroll
    for (int dt = 0; dt < 4; ++dt) {
      const int rb = wk * 4096 + (dt * 16 + l16) * 64;
      vf[dt][0] = *(const bf16x8*)&Vc[rb + kgA];
      vf[dt][1] = *(const bf16x8*)&Vc[rb + kgB];
    }

    // ---- rowsums + O^T += V^T P^T (40 MFMA) ----
    __builtin_amdgcn_s_setprio(1);
#pragma unroll
    for (int qt = 0; qt < 4; ++qt) {
      accL[qt] = MFMA16(ones, pf[0][qt], accL[qt]);
      accL[qt] = MFMA16(ones, pf[1][qt], accL[qt]);
    }
#pragma unroll
    for (int dt = 0; dt < 4; ++dt)
#pragma unroll
      for (int qt = 0; qt < 4; ++qt) {
        accO[dt][qt] = MFMA16(vf[dt][0], pf[0][qt], accO[dt][qt]);
        accO[dt][qt] = MFMA16(vf[dt][1], pf[1][qt], accO[dt][qt]);
      }
    __builtin_amdgcn_s_setprio(0);
  }
#undef STAGE_KV

  // ---- cross-wk reduce through LDS (reuse Ks/Vs; conflict-free b128) ----
  __syncthreads();                      // all tile-15 LDS reads complete
  float* redO = (float*)&Ks[0][0];      // 32 f32x4-slots x 64 lanes = 32 KB
  float* redL = (float*)&Vs[0][0];      // 128 f32
  if (wk == 1) {
#pragma unroll
    for (int dt = 0; dt < 4; ++dt)
#pragma unroll
      for (int qt = 0; qt < 4; ++qt)
        *(f32x4*)&redO[((wq * 16 + dt * 4 + qt) << 8) + lane * 4] = accO[dt][qt];
    if (quad == 0) {
#pragma unroll
      for (int qt = 0; qt < 4; ++qt)
        redL[wq * 64 + qt * 16 + l16] = accL[qt][0];
    }
  }
  __syncthreads();
  if (wk == 0) {
#pragma unroll
    for (int dt = 0; dt < 4; ++dt)
#pragma unroll
      for (int qt = 0; qt < 4; ++qt)
        accO[dt][qt] += *(const f32x4*)&redO[((wq * 16 + dt * 4 + qt) << 8) + lane * 4];
#pragma unroll
    for (int qt = 0; qt < 4; ++qt) {
      const float inv = 1.f / (accL[qt][0] + redL[wq * 64 + qt * 16 + l16]);
      const int qrow = q0w + qt * 16 + l16;
#pragma unroll
      for (int dt = 0; dt < 4; ++dt) {
        ushort4 pk;
        pk.x = f2bf(accO[dt][qt][0] * inv);
        pk.y = f2bf(accO[dt][qt][1] * inv);
        pk.z = f2bf(accO[dt][qt][2] * inv);
        pk.w = f2bf(accO[dt][qt][3] * inv);
        *(ushort4*)&o[(size_t)(b * S + qrow) * 1024 + h * 64 + dt * 16 + quad * 4] = pk;
      }
    }
  }
}

// ---------------- launch ----------------

extern "C" void kernel_launch(void* const* d_in, const int* in_sizes, int n_in,
                              void* d_out, int out_size, void* d_ws, size_t ws_size,
                              hipStream_t stream) {
  const float* x = (const float*)d_in[0];
  const float* w_qkv = (const float*)d_in[1];
  const float* b_qkv = (const float*)d_in[2];
  const float* w_out = (const float*)d_in[3];
  const float* b_out = (const float*)d_in[4];
  float* out = (float*)d_out;

  u16* xb = (u16*)d_ws;                 // [4096,1024]
  u16* wqT = xb + 4096 * 1024;          // [3072,1024]
  u16* woT = wqT + 3072 * 1024;         // [1024,1024]
  u16* qb = woT + 1024 * 1024;          // [32,2048,64] (pre-scaled)
  u16* kb = qb + 4194304;               // [32,2048,64]
  u16* vb = kb + 4194304;               // [32,64,2048]
  u16* ao = vb + 4194304;               // [4096,1024]

  prep<<<8192, 256, 0, stream>>>(x, w_qkv, w_out, xb, wqT, woT);
  gemm_qkv<<<dim3(32, 24), 256, 0, stream>>>(xb, wqT, b_qkv, qb, kb, vb,
                                             4096, 3072, 1024);
  attn_fa<<<512, 256, 0, stream>>>(qb, kb, vb, ao);
  gemm_out<<<dim3(64, 8), 256, 0, stream>>>(ao, woT, b_out, out,
                                            4096, 1024, 1024);
}